// Round 3
// baseline (31.277 us; speedup 1.0000x reference)
//
#include <hip/hip_runtime.h>

// Problem geometry (fixed by the reference):
//   prev_x: [128, 256, 28, 28] f32  -> PREV_CHW = 200704 per batch
//   curr_x: [128, 512, 14, 14] f32  -> CURR_CHW = 100352 per batch
//   out:    [256, 28, 28] f32       -> 200704 elements
// out[chw] = sum_b (prev_x[b,chw] > 0) * popcount_pos(curr_x[b])
// All values are integers <= 128*100352 < 2^24 -> exact in fp32 in any order.
//
// R3 design notes:
//  - R2 fixed fills/atomics; residual gap vs the 24.6 us roofline traced to
//    corr_kernel load imbalance (392 blocks / 256 CUs = 1.53 blocks/CU ->
//    half the CUs carry 2x traffic).
//  - Now: float2 output unit, 784 blocks x 128 threads = 100352 threads,
//    exactly one unit each; 3.06 blocks/CU -> worst-case 1.3x imbalance on
//    16/256 CUs only. Coalescing: 64 lanes x 8 B = 512 B/instr contiguous.

constexpr int NB       = 128;
constexpr int PREV_CHW = 256 * 28 * 28;   // 200704
constexpr int CURR_CHW = 512 * 14 * 14;   // 100352
constexpr int PREV_V2  = PREV_CHW / 2;    // 100352 float2 columns
constexpr int CURR_V4  = CURR_CHW / 4;    // 25088
constexpr int QUARTER  = CURR_V4 / 4;     // 6272 float4 per (batch, quarter)

// Kernel 1: partial positive-count of curr_x. grid = (128 batches, 4 quarters),
// 512 blocks total -> exactly 2 blocks/CU, no init, no atomics.
__global__ void __launch_bounds__(256)
count_pos_kernel(const float* __restrict__ curr, float* __restrict__ partial) {
    const int b = blockIdx.x;
    const int q = blockIdx.y;
    const float4* p = reinterpret_cast<const float4*>(curr)
                      + (size_t)b * CURR_V4 + (size_t)q * QUARTER;
    int cnt = 0;
    for (int i = threadIdx.x; i < QUARTER; i += 256) {
        float4 v = p[i];
        cnt += (v.x > 0.0f);
        cnt += (v.y > 0.0f);
        cnt += (v.z > 0.0f);
        cnt += (v.w > 0.0f);
    }
    // wave64 shuffle reduction, then 4-wave LDS fold
    #pragma unroll
    for (int off = 32; off > 0; off >>= 1)
        cnt += __shfl_down(cnt, off, 64);
    __shared__ int wsum[4];
    if ((threadIdx.x & 63) == 0)
        wsum[threadIdx.x >> 6] = cnt;
    __syncthreads();
    if (threadIdx.x == 0)
        partial[q * NB + b] = (float)(wsum[0] + wsum[1] + wsum[2] + wsum[3]);
}

// Kernel 2: out[chw] = sum_b (prev>0) * sums[b]. One float2 of output per
// thread; each thread walks all 128 batches -> single direct store, no init.
// grid = 784 blocks x 128 threads = 100352 threads, exact cover of PREV_V2.
__global__ void __launch_bounds__(128)
corr_kernel(const float* __restrict__ prev, const float* __restrict__ partial,
            float* __restrict__ out) {
    __shared__ float s_sum[NB];
    const int t = threadIdx.x;
    // fold the 4 quarter-partials per batch (t indexes batch, 128 threads = NB)
    s_sum[t] = partial[t] + partial[NB + t] + partial[2 * NB + t] + partial[3 * NB + t];
    __syncthreads();

    const int u = blockIdx.x * 128 + t;          // float2 column, 0..100351
    const float2* pv = reinterpret_cast<const float2*>(prev) + u;

    float2 acc = make_float2(0.0f, 0.0f);
    #pragma unroll 16
    for (int b = 0; b < NB; ++b) {
        const float2 v = pv[(size_t)b * PREV_V2];  // coalesced 8 B/lane
        const float s = s_sum[b];                  // wave-uniform LDS broadcast
        acc.x += (v.x > 0.0f) ? s : 0.0f;
        acc.y += (v.y > 0.0f) ? s : 0.0f;
    }
    reinterpret_cast<float2*>(out)[u] = acc;       // single direct store
}

extern "C" void kernel_launch(void* const* d_in, const int* in_sizes, int n_in,
                              void* d_out, int out_size, void* d_ws, size_t ws_size,
                              hipStream_t stream) {
    const float* prev = (const float*)d_in[0];
    const float* curr = (const float*)d_in[1];
    float* out     = (float*)d_out;
    float* partial = (float*)d_ws;   // 512 floats of scratch, written before read

    count_pos_kernel<<<dim3(NB, 4), 256, 0, stream>>>(curr, partial);
    corr_kernel<<<PREV_V2 / 128, 128, 0, stream>>>(prev, partial, out);
}